// Round 6
// baseline (2489.775 us; speedup 1.0000x reference)
//
#include <hip/hip_runtime.h>
#include <stdint.h>

#define NHITS 100000
#define NOBJ  1024
#define HALF  50000
#define HALF_PAIRS 51200000u   // NHITS*NOBJ/2
#define F0 0.125f

typedef float v2f __attribute__((ext_vector_type(2)));

// ---------------- ws layout (bytes) ----------------
// 0:   double v_att_sum
// 8:   double v_rep_sum
// 16:  double coward_sum
// 24:  double noise_sum
// 32:  ull    noise_cnt
// 40:  u32    nrep           (pure repulsive candidates)
// 44:  u32    rec_ctr        (records with u < F0)
// 48:  float  freq
// 64:  ull    packed[1024]                         (64..8256)
// 8256:   float arec[1024*16] {x[12], qa, xxa,0,0} (8256..73792)
// 73792:  float q_arr[100000]                      (73792..473792)
// 473792: float xx_arr[100000]                     (473792..873792)
// 873792: float2 recs[cap2]  {u, val}

#define REC_OFF 873792ull

__device__ inline uint32_t rotl32(uint32_t x, int n) {
    return (x << n) | (x >> (32 - n));
}

__device__ inline void threefry2x32(uint32_t k0, uint32_t k1,
                                    uint32_t x0, uint32_t x1,
                                    uint32_t& o0, uint32_t& o1) {
    uint32_t ks2 = k0 ^ k1 ^ 0x1BD11BDAu;
    x0 += k0; x1 += k1;
#define TF_ROUND(r) { x0 += x1; x1 = rotl32(x1, r); x1 ^= x0; }
    TF_ROUND(13) TF_ROUND(15) TF_ROUND(26) TF_ROUND(6)
    x0 += k1;  x1 += ks2 + 1u;
    TF_ROUND(17) TF_ROUND(29) TF_ROUND(16) TF_ROUND(24)
    x0 += ks2; x1 += k0 + 2u;
    TF_ROUND(13) TF_ROUND(15) TF_ROUND(26) TF_ROUND(6)
    x0 += k0;  x1 += k1 + 3u;
    TF_ROUND(17) TF_ROUND(29) TF_ROUND(16) TF_ROUND(24)
    x0 += k1;  x1 += ks2 + 4u;
    TF_ROUND(13) TF_ROUND(15) TF_ROUND(26) TF_ROUND(6)
    x0 += ks2; x1 += k0 + 5u;
#undef TF_ROUND
    o0 = x0; o1 = x1;
}

__device__ inline float tf_uniform(uint32_t bits) {
    return __uint_as_float((bits >> 9) | 0x3f800000u) - 1.0f;
}

__device__ inline double waveReduceD(double v) {
    for (int off = 32; off > 0; off >>= 1) v += __shfl_down(v, off, 64);
    return v;
}
__device__ inline unsigned int waveReduceU(unsigned int v) {
    for (int off = 32; off > 0; off >>= 1) v += __shfl_down(v, off, 64);
    return v;
}

#define DOT12(XA, XB, XC, A, B, C) \
    fmaf((XC).w, (C).w, fmaf((XC).z, (C).z, fmaf((XC).y, (C).y, fmaf((XC).x, (C).x, \
    fmaf((XB).w, (B).w, fmaf((XB).z, (B).z, fmaf((XB).y, (B).y, fmaf((XB).x, (B).x, \
    fmaf((XA).w, (A).w, fmaf((XA).z, (A).z, fmaf((XA).y, (A).y, (XA).x * (A).x)))))))))))

#define SS12(XA, XB, XC) DOT12(XA, XB, XC, XA, XB, XC)

// ---------------- kernels ----------------

__global__ void k_init(unsigned long long* packed, unsigned long long* hdr) {
    int t = blockIdx.x * blockDim.x + threadIdx.x;
    if (t < NOBJ) packed[t] = 0xFFFFFFFFull;
    if (t < 8)    hdr[t] = 0ull;
}

__global__ void k_hits(const float* __restrict__ beta,
                       const float* __restrict__ x,
                       const int* __restrict__ oid,
                       unsigned long long* __restrict__ packed,
                       float* __restrict__ q_arr,
                       float* __restrict__ xx_arr,
                       double* __restrict__ noise_sum,
                       unsigned long long* __restrict__ noise_cnt) {
    int j = blockIdx.x * blockDim.x + threadIdx.x;
    float nb = 0.0f;
    unsigned int nc = 0;
    if (j < NHITS) {
        float b = beta[j];
        int o = oid[j];
        float a = atanhf(b);
        float q = a * a + 0.1f;
        q_arr[j] = q;
        const float4* x4 = (const float4*)x;
        float4 A = x4[j * 3 + 0], B = x4[j * 3 + 1], C = x4[j * 3 + 2];
        xx_arr[j] = SS12(A, B, C);
        if (o > 0) {
            unsigned long long p =
                ((unsigned long long)__float_as_uint(q) << 32) |
                (unsigned long long)(0xFFFFFFFFu - (unsigned)j);
            atomicMax(&packed[o - 1], p);
        } else {
            nb = b; nc = 1;
        }
    }
    double rb = waveReduceD((double)nb);
    unsigned int rc = waveReduceU(nc);
    if ((threadIdx.x & 63) == 0) {
        if (rb != 0.0) atomicAdd(noise_sum, rb);
        if (rc)        atomicAdd(noise_cnt, (unsigned long long)rc);
    }
}

__global__ void k_alphas(const unsigned long long* __restrict__ packed,
                         const float* __restrict__ x,
                         const float* __restrict__ beta,
                         const float* __restrict__ q_arr,
                         const float* __restrict__ xx_arr,
                         float* __restrict__ arec,
                         double* __restrict__ coward_sum) {
    int k = blockIdx.x * blockDim.x + threadIdx.x;
    double c = 0.0;
    if (k < NOBJ) {
        unsigned idx = 0xFFFFFFFFu - (unsigned)(packed[k] & 0xFFFFFFFFull);
        const float4* x4 = (const float4*)x;
        float4 A = x4[idx * 3 + 0];
        float4 B = x4[idx * 3 + 1];
        float4 C = x4[idx * 3 + 2];
        float4 D;
        D.x = q_arr[idx]; D.y = xx_arr[idx]; D.z = 0.f; D.w = 0.f;
        float4* ar = (float4*)arec;
        ar[k * 4 + 0] = A;
        ar[k * 4 + 1] = B;
        ar[k * 4 + 2] = C;
        ar[k * 4 + 3] = D;
        c = 1.0 - (double)beta[idx];
    }
    double rc = waveReduceD(c);
    if ((threadIdx.x & 63) == 0) atomicAdd(coward_sum, rc);
}

// fused scan: masks + n_rep + v_att + (u<F0) candidate records
__global__ __launch_bounds__(256)
void k_scan(const float* __restrict__ x,
            const float* __restrict__ q_arr,
            const float* __restrict__ xx_arr,
            const int* __restrict__ oid,
            const float* __restrict__ arec,
            float2* __restrict__ recs,
            unsigned int* __restrict__ nrep,
            unsigned int* __restrict__ rec_ctr,
            unsigned int cap2,
            double* __restrict__ v_att_sum) {
    __shared__ float4 spack[512];       // [k][0..3] packed float4
    __shared__ float  sT[14 * 128];     // [d][k] transposed (12 x, 12=qa, 13=xxa)
    __shared__ double sd[4];
    __shared__ unsigned int su[4];

    const int tid = threadIdx.x;
    const int kb = blockIdx.y * 128;
    const float4* ar4 = (const float4*)arec;
#pragma unroll
    for (int i0 = 0; i0 < 2; ++i0) {
        int i = tid + i0 * 256;
        float4 v = ar4[kb * 4 + i];
        spack[i] = v;
        int k = i >> 2, p = i & 3;
        if (p < 3) {
            sT[(p * 4 + 0) * 128 + k] = v.x;
            sT[(p * 4 + 1) * 128 + k] = v.y;
            sT[(p * 4 + 2) * 128 + k] = v.z;
            sT[(p * 4 + 3) * 128 + k] = v.w;
        } else {
            sT[12 * 128 + k] = v.x;   // qa
            sT[13 * 128 + k] = v.y;   // |x_a|^2
        }
    }
    __syncthreads();

    const int t = blockIdx.x * 256 + tid;
    const bool valid = t < HALF;
    const int j0 = valid ? t : 0;
    const int j1 = j0 + HALF;
    const float4* x4 = (const float4*)x;

    v2f X[12];
    {
        float4 A0 = x4[j0 * 3 + 0], B0 = x4[j0 * 3 + 1], C0 = x4[j0 * 3 + 2];
        float4 A1 = x4[j1 * 3 + 0], B1 = x4[j1 * 3 + 1], C1 = x4[j1 * 3 + 2];
        X[0]  = (v2f){A0.x, A1.x}; X[1]  = (v2f){A0.y, A1.y};
        X[2]  = (v2f){A0.z, A1.z}; X[3]  = (v2f){A0.w, A1.w};
        X[4]  = (v2f){B0.x, B1.x}; X[5]  = (v2f){B0.y, B1.y};
        X[6]  = (v2f){B0.z, B1.z}; X[7]  = (v2f){B0.w, B1.w};
        X[8]  = (v2f){C0.x, C1.x}; X[9]  = (v2f){C0.y, C1.y};
        X[10] = (v2f){C0.z, C1.z}; X[11] = (v2f){C0.w, C1.w};
    }
    v2f xxp = (v2f){xx_arr[j0], xx_arr[j1]};
    if (!valid) xxp = (v2f){3e9f, 3e9f};
    v2f qp = (v2f){q_arr[j0], q_arr[j1]};
    int o0 = valid ? oid[j0] : 0;
    int o1 = valid ? oid[j1] : 0;

    // ---- mask build (uniform k loop, packed both hits) ----
    uint32_t m0[4], m1[4];
#pragma unroll
    for (int g = 0; g < 4; ++g) {
        uint32_t a0 = 0, a1 = 0, bit = 1u;
        for (int kk = 0; kk < 32; ++kk, bit += bit) {
            int k = g * 32 + kk;
            float4 A = spack[k * 4 + 0];
            float4 B = spack[k * 4 + 1];
            float4 C = spack[k * 4 + 2];
            float a2 = sT[13 * 128 + k];
            v2f dot = X[0] * (v2f){A.x, A.x};
            dot = __builtin_elementwise_fma(X[1],  (v2f){A.y, A.y}, dot);
            dot = __builtin_elementwise_fma(X[2],  (v2f){A.z, A.z}, dot);
            dot = __builtin_elementwise_fma(X[3],  (v2f){A.w, A.w}, dot);
            dot = __builtin_elementwise_fma(X[4],  (v2f){B.x, B.x}, dot);
            dot = __builtin_elementwise_fma(X[5],  (v2f){B.y, B.y}, dot);
            dot = __builtin_elementwise_fma(X[6],  (v2f){B.z, B.z}, dot);
            dot = __builtin_elementwise_fma(X[7],  (v2f){B.w, B.w}, dot);
            dot = __builtin_elementwise_fma(X[8],  (v2f){C.x, C.x}, dot);
            dot = __builtin_elementwise_fma(X[9],  (v2f){C.y, C.y}, dot);
            dot = __builtin_elementwise_fma(X[10], (v2f){C.z, C.z}, dot);
            dot = __builtin_elementwise_fma(X[11], (v2f){C.w, C.w}, dot);
            v2f d2 = __builtin_elementwise_fma((v2f){-2.f, -2.f}, dot, xxp);
            d2 = d2 + (v2f){a2, a2};
            a0 |= (d2[0] < 1.0f) ? bit : 0u;
            a1 |= (d2[1] < 1.0f) ? bit : 0u;
        }
        m0[g] = a0; m1[g] = a1;
    }
    uint64_t c0 = (uint64_t)m0[0] | ((uint64_t)m0[1] << 32);
    uint64_t c1 = (uint64_t)m0[2] | ((uint64_t)m0[3] << 32);
    uint64_t c2 = (uint64_t)m1[0] | ((uint64_t)m1[1] << 32);
    uint64_t c3 = (uint64_t)m1[2] | ((uint64_t)m1[3] << 32);

    // ---- attractive term + clear att bit ----
    double vatt = 0.0;
    if (o0 > 0) {
        int rel = o0 - 1 - kb;
        if (rel >= 0 && rel < 128) {
            if (rel < 64) c0 &= ~(1ull << rel);
            else          c1 &= ~(1ull << (rel - 64));
            float dot = X[0][0] * sT[0 * 128 + rel];
#pragma unroll
            for (int d = 1; d < 12; ++d)
                dot = fmaf(X[d][0], sT[d * 128 + rel], dot);
            float d2 = fmaf(-2.0f, dot, xxp[0]) + sT[13 * 128 + rel];
            vatt += (double)((qp[0] * sT[12 * 128 + rel]) * fmaxf(d2, 0.0f));
        }
    }
    if (o1 > 0) {
        int rel = o1 - 1 - kb;
        if (rel >= 0 && rel < 128) {
            if (rel < 64) c2 &= ~(1ull << rel);
            else          c3 &= ~(1ull << (rel - 64));
            float dot = X[0][1] * sT[0 * 128 + rel];
#pragma unroll
            for (int d = 1; d < 12; ++d)
                dot = fmaf(X[d][1], sT[d * 128 + rel], dot);
            float d2 = fmaf(-2.0f, dot, xxp[1]) + sT[13 * 128 + rel];
            vatt += (double)((qp[1] * sT[12 * 128 + rel]) * fmaxf(d2, 0.0f));
        }
    }

    unsigned int cnt = (unsigned)(__popcll(c0) + __popcll(c1) +
                                  __popcll(c2) + __popcll(c3));

    // ---- candidate loop: threefry + (u<F0) record push ----
    const int lane = tid & 63;
    for (;;) {
        bool have = (c0 | c1 | c2 | c3) != 0ull;
        if (__ballot(have) == 0ull) break;
        int kl = 0; bool s1 = false; bool act = false;
        if (c0)      { int b = (int)__builtin_ctzll(c0); c0 &= c0 - 1; kl = b;      act = true; }
        else if (c1) { int b = (int)__builtin_ctzll(c1); c1 &= c1 - 1; kl = 64 + b; act = true; }
        else if (c2) { int b = (int)__builtin_ctzll(c2); c2 &= c2 - 1; kl = b;      s1 = true; act = true; }
        else if (c3) { int b = (int)__builtin_ctzll(c3); c3 &= c3 - 1; kl = 64 + b; s1 = true; act = true; }
        float u = 1e9f, val = 0.f; bool push = false;
        if (act) {
            float a0v = sT[0 * 128 + kl];
            v2f dotp = X[0] * (v2f){a0v, a0v};
#pragma unroll
            for (int d = 1; d < 12; ++d) {
                float av = sT[d * 128 + kl];
                dotp = __builtin_elementwise_fma(X[d], (v2f){av, av}, dotp);
            }
            float dot = s1 ? dotp[1] : dotp[0];
            float xxv = s1 ? xxp[1] : xxp[0];
            float qv  = s1 ? qp[1]  : qp[0];
            float qav = sT[12 * 128 + kl];
            float a2v = sT[13 * 128 + kl];
            float d2 = fmaf(-2.0f, dot, xxv) + a2v;
            float dist = sqrtf(fmaxf(fmaxf(d2, 0.0f), 1e-12f));
            int j = s1 ? j1 : j0;
            uint32_t f = (uint32_t)j * NOBJ + (uint32_t)(kb + kl);
            uint32_t xa = s1 ? (f - HALF_PAIRS) : f;
            uint32_t b0_, b1_;
            threefry2x32(0u, 42u, xa, xa + HALF_PAIRS, b0_, b1_);
            uint32_t bits = s1 ? b1_ : b0_;
            u = tf_uniform(bits);
            val = (qv * qav) * (1.0f - dist);
            push = u < F0;
        }
        unsigned long long pb = __ballot(push);
        if (pb) {
            int lead = (int)__builtin_ctzll(pb);
            unsigned int base = 0;
            if (lane == lead) base = atomicAdd(rec_ctr, (unsigned)__popcll(pb));
            base = __shfl(base, lead, 64);
            if (push) {
                unsigned int pos = base + (unsigned)__popcll(pb & ((1ull << lane) - 1ull));
                if (pos < cap2) recs[pos] = make_float2(u, val);
            }
        }
    }

    // ---- reductions ----
    double rv = waveReduceD(vatt);
    unsigned int rc = waveReduceU(cnt);
    if (lane == 0) { sd[tid >> 6] = rv; su[tid >> 6] = rc; }
    __syncthreads();
    if (tid == 0) {
        double s = sd[0] + sd[1] + sd[2] + sd[3];
        if (s != 0.0) atomicAdd(v_att_sum, s);
        unsigned int c = su[0] + su[1] + su[2] + su[3];
        if (c) atomicAdd(nrep, c);
    }
}

__global__ void k_freq(const unsigned int* __restrict__ nrep,
                       float* __restrict__ freq) {
    unsigned int n = *nrep;
    if (n < 1u) n = 1u;
    float f = 100000.0f / (float)n;
    *freq = fminf(f, 1.0f);
}

// sum accepted records (u < freq); skipped if fallback conditions hold
__global__ __launch_bounds__(256)
void k_rep_sum(const float2* __restrict__ recs,
               const unsigned int* __restrict__ rec_ctr,
               const float* __restrict__ freq_ptr,
               unsigned int cap2,
               double* __restrict__ acc_out) {
    float fr = *freq_ptr;
    unsigned int n = *rec_ctr;
    if (fr >= F0 || n > cap2) return;
    double acc = 0.0;
    const unsigned int stride = gridDim.x * 256;
    for (unsigned int i = blockIdx.x * 256 + threadIdx.x; i < n; i += stride) {
        float2 r = recs[i];
        if (r.x < fr) acc += (double)r.y;
    }
    __shared__ double sd[4];
    double rv = waveReduceD(acc);
    if ((threadIdx.x & 63) == 0) sd[threadIdx.x >> 6] = rv;
    __syncthreads();
    if (threadIdx.x == 0) {
        double s = sd[0] + sd[1] + sd[2] + sd[3];
        if (s != 0.0) atomicAdd(acc_out, s);
    }
}

// fallback (freq >= F0 or record overflow): dense rescan + sample. Dormant.
__global__ __launch_bounds__(256)
void k_rep_fb(const float* __restrict__ x,
              const float* __restrict__ q_arr,
              const float* __restrict__ xx_arr,
              const int* __restrict__ oid,
              const float* __restrict__ arec,
              const unsigned int* __restrict__ rec_ctr,
              unsigned int cap2,
              const float* __restrict__ freq_ptr,
              double* __restrict__ acc_out) {
    const float freq = *freq_ptr;
    if (!(freq >= F0 || *rec_ctr > cap2)) return;
    __shared__ double sacc[4];
    const int tid = threadIdx.x;
    int t = blockIdx.x * 256 + tid;
    bool valid = t < HALF;
    int j0 = valid ? t : 0;
    int j1 = j0 + HALF;
    const float4* x4 = (const float4*)x;
    float4 X0a = x4[j0 * 3 + 0], X0b = x4[j0 * 3 + 1], X0c = x4[j0 * 3 + 2];
    float4 X1a = x4[j1 * 3 + 0], X1b = x4[j1 * 3 + 1], X1c = x4[j1 * 3 + 2];
    float xx0 = valid ? xx_arr[j0] : 3e9f;
    float xx1 = valid ? xx_arr[j1] : 3e9f;
    int o0 = oid[j0], o1 = oid[j1];
    const float4* ar = (const float4*)arec;
    const int kb = blockIdx.y * 128;

    uint32_t m0[4], m1[4];
#pragma unroll
    for (int g = 0; g < 4; ++g) {
        uint32_t a0 = 0, a1 = 0, bit = 1u;
        int kbase = kb + g * 32;
        for (int kk = 0; kk < 32; ++kk, bit += bit) {
            int k = kbase + kk;
            float4 A = ar[k * 4 + 0];
            float4 B = ar[k * 4 + 1];
            float4 C = ar[k * 4 + 2];
            float a2 = arec[k * 16 + 13];
            float d0 = DOT12(X0a, X0b, X0c, A, B, C);
            float d1 = DOT12(X1a, X1b, X1c, A, B, C);
            float t0 = fmaf(-2.0f, d0, xx0) + a2;
            float t1 = fmaf(-2.0f, d1, xx1) + a2;
            a0 |= (t0 < 1.0f) ? bit : 0u;
            a1 |= (t1 < 1.0f) ? bit : 0u;
        }
        m0[g] = a0; m1[g] = a1;
    }
    if (valid && o0 > 0) {
        int rel = o0 - 1 - kb;
        if (rel >= 0 && rel < 128) m0[rel >> 5] &= ~(1u << (rel & 31));
    }
    if (valid && o1 > 0) {
        int rel = o1 - 1 - kb;
        if (rel >= 0 && rel < 128) m1[rel >> 5] &= ~(1u << (rel & 31));
    }

    double acc = 0.0;
#define FB_SLOT(MARR, J, XA, XB, XC, XX, S1)                                    \
    for (int g = 0; g < 4; ++g) {                                               \
        uint32_t m = MARR[g];                                                   \
        while (m) {                                                             \
            int kk = __ffs(m) - 1; m &= m - 1;                                  \
            int k = kb + g * 32 + kk;                                           \
            uint32_t f = (uint32_t)(J) * NOBJ + (uint32_t)k;                    \
            uint32_t xa_ = (S1) ? (f - HALF_PAIRS) : f;                         \
            uint32_t b0_, b1_;                                                  \
            threefry2x32(0u, 42u, xa_, xa_ + HALF_PAIRS, b0_, b1_);             \
            float u = tf_uniform((S1) ? b1_ : b0_);                             \
            if (u < freq) {                                                     \
                float4 A = ar[k * 4 + 0], B = ar[k * 4 + 1], C = ar[k * 4 + 2], D = ar[k * 4 + 3]; \
                float dot = DOT12(XA, XB, XC, A, B, C);                         \
                float d2 = fmaf(-2.0f, dot, XX) + D.y;                          \
                float dist = sqrtf(fmaxf(fmaxf(d2, 0.0f), 1e-12f));             \
                acc += (double)((q_arr[J] * D.x) * (1.0f - dist));              \
            }                                                                   \
        }                                                                       \
    }
    FB_SLOT(m0, j0, X0a, X0b, X0c, xx0, false)
    FB_SLOT(m1, j1, X1a, X1b, X1c, xx1, true)
#undef FB_SLOT

    double rv = waveReduceD(acc);
    if ((tid & 63) == 0) sacc[tid >> 6] = rv;
    __syncthreads();
    if (tid == 0) {
        double s = sacc[0] + sacc[1] + sacc[2] + sacc[3];
        if (s != 0.0) atomicAdd(acc_out, s);
    }
}

__global__ void k_final(const double* __restrict__ accs,
                        const unsigned long long* __restrict__ noise_cnt,
                        const float* __restrict__ freq,
                        float* __restrict__ out) {
    double v_att = accs[0] / (double)NHITS;
    double v_rep = accs[1] / (double)(*freq) / (double)NHITS;
    double l_cow = accs[2] / (double)NOBJ;
    unsigned long long nc = *noise_cnt;
    if (nc < 1ull) nc = 1ull;
    double l_noise = accs[3] / ((double)nc + 1e-9);
    double loss = v_att + v_rep + l_cow + 0.1 * l_noise;
    out[0] = (float)v_att;
    out[1] = (float)v_rep;
    out[2] = (float)l_cow;
    out[3] = (float)l_noise;
    out[4] = (float)loss;
}

// ---------------- launcher ----------------

extern "C" void kernel_launch(void* const* d_in, const int* in_sizes, int n_in,
                              void* d_out, int out_size, void* d_ws, size_t ws_size,
                              hipStream_t stream) {
    const float* beta = (const float*)d_in[0];
    const float* x    = (const float*)d_in[1];
    const int*   oid  = (const int*)d_in[2];
    float* out = (float*)d_out;

    char* ws = (char*)d_ws;
    double* v_att_sum = (double*)(ws + 0);
    double* v_rep_sum = (double*)(ws + 8);
    double* coward_sum = (double*)(ws + 16);
    double* noise_sum = (double*)(ws + 24);
    unsigned long long* noise_cnt = (unsigned long long*)(ws + 32);
    unsigned int* nrep = (unsigned int*)(ws + 40);
    unsigned int* rec_ctr = (unsigned int*)(ws + 44);
    float* freq = (float*)(ws + 48);
    unsigned long long* packed = (unsigned long long*)(ws + 64);
    float* arec = (float*)(ws + 8256);
    float* q_arr = (float*)(ws + 73792);
    float* xx_arr = (float*)(ws + 473792);
    float2* recs = (float2*)(ws + REC_OFF);

    unsigned int cap2 = 0;
    if (ws_size > REC_OFF + 8) {
        size_t c = (ws_size - REC_OFF) / 8;
        cap2 = (c > 0xF0000000ull) ? 0xF0000000u : (unsigned int)c;
    }

    k_init<<<4, 256, 0, stream>>>(packed, (unsigned long long*)ws);
    k_hits<<<(NHITS + 255) / 256, 256, 0, stream>>>(beta, x, oid, packed,
                                                    q_arr, xx_arr,
                                                    noise_sum, noise_cnt);
    k_alphas<<<4, 256, 0, stream>>>(packed, x, beta, q_arr, xx_arr,
                                    arec, coward_sum);

    dim3 gs((HALF + 255) / 256, 8);
    k_scan<<<gs, 256, 0, stream>>>(x, q_arr, xx_arr, oid, arec,
                                   recs, nrep, rec_ctr, cap2, v_att_sum);

    k_freq<<<1, 1, 0, stream>>>(nrep, freq);

    k_rep_sum<<<256, 256, 0, stream>>>(recs, rec_ctr, freq, cap2, v_rep_sum);
    k_rep_fb<<<gs, 256, 0, stream>>>(x, q_arr, xx_arr, oid, arec,
                                     rec_ctr, cap2, freq, v_rep_sum);

    k_final<<<1, 1, 0, stream>>>((double*)ws, noise_cnt, freq, out);
}

// Round 7
// 255.623 us; speedup vs baseline: 9.7400x; 9.7400x over previous
//
#include <hip/hip_runtime.h>
#include <stdint.h>

#define NHITS 100000
#define NOBJ  1024
#define HALF  50000
#define HALF_PAIRS 51200000u   // NHITS*NOBJ/2

typedef float v2f __attribute__((ext_vector_type(2)));

// ---------------- ws layout (bytes) ----------------
// 0:   double v_att_sum
// 8:   double v_rep_sum
// 16:  double coward_sum
// 24:  double noise_sum
// 32:  ull    noise_cnt
// 40:  u32    nrep          (pure repulsive: d2<1 and not attractive)
// 48:  float  freq
// 64:   ull   packed[1024]                        (64..8256)
// 8256: float arec[1024*16] {x[12], qa, xxa,0,0}  (8256..73792)
// 73792:  float q_arr[100000]                     (73792..473792)
// 473792: float xx_arr[100000]                    (473792..873792)
// 873792: u32 maskbuf[32][100000] = 12.8MB        (873792..13673792)

#define MASK_OFF 873792ull
#define WS_NEED (MASK_OFF + 32ull * NHITS * 4ull)

__device__ inline uint32_t rotl32(uint32_t x, int n) {
    return (x << n) | (x >> (32 - n));
}

__device__ inline void threefry2x32(uint32_t k0, uint32_t k1,
                                    uint32_t x0, uint32_t x1,
                                    uint32_t& o0, uint32_t& o1) {
    uint32_t ks2 = k0 ^ k1 ^ 0x1BD11BDAu;
    x0 += k0; x1 += k1;
#define TF_ROUND(r) { x0 += x1; x1 = rotl32(x1, r); x1 ^= x0; }
    TF_ROUND(13) TF_ROUND(15) TF_ROUND(26) TF_ROUND(6)
    x0 += k1;  x1 += ks2 + 1u;
    TF_ROUND(17) TF_ROUND(29) TF_ROUND(16) TF_ROUND(24)
    x0 += ks2; x1 += k0 + 2u;
    TF_ROUND(13) TF_ROUND(15) TF_ROUND(26) TF_ROUND(6)
    x0 += k0;  x1 += k1 + 3u;
    TF_ROUND(17) TF_ROUND(29) TF_ROUND(16) TF_ROUND(24)
    x0 += k1;  x1 += ks2 + 4u;
    TF_ROUND(13) TF_ROUND(15) TF_ROUND(26) TF_ROUND(6)
    x0 += ks2; x1 += k0 + 5u;
#undef TF_ROUND
    o0 = x0; o1 = x1;
}

__device__ inline float tf_uniform(uint32_t bits) {
    return __uint_as_float((bits >> 9) | 0x3f800000u) - 1.0f;
}

__device__ inline double waveReduceD(double v) {
    for (int off = 32; off > 0; off >>= 1) v += __shfl_down(v, off, 64);
    return v;
}
__device__ inline unsigned int waveReduceU(unsigned int v) {
    for (int off = 32; off > 0; off >>= 1) v += __shfl_down(v, off, 64);
    return v;
}

#define DOT12(XA, XB, XC, A, B, C) \
    fmaf((XC).w, (C).w, fmaf((XC).z, (C).z, fmaf((XC).y, (C).y, fmaf((XC).x, (C).x, \
    fmaf((XB).w, (B).w, fmaf((XB).z, (B).z, fmaf((XB).y, (B).y, fmaf((XB).x, (B).x, \
    fmaf((XA).w, (A).w, fmaf((XA).z, (A).z, fmaf((XA).y, (A).y, (XA).x * (A).x)))))))))))

#define SS12(XA, XB, XC) DOT12(XA, XB, XC, XA, XB, XC)

// ---------------- kernels ----------------

__global__ void k_init(unsigned long long* packed, unsigned long long* hdr) {
    int t = blockIdx.x * blockDim.x + threadIdx.x;
    if (t < NOBJ) packed[t] = 0xFFFFFFFFull;
    if (t < 8)    hdr[t] = 0ull;
}

__global__ void k_hits(const float* __restrict__ beta,
                       const float* __restrict__ x,
                       const int* __restrict__ oid,
                       unsigned long long* __restrict__ packed,
                       float* __restrict__ q_arr,
                       float* __restrict__ xx_arr,
                       double* __restrict__ noise_sum,
                       unsigned long long* __restrict__ noise_cnt) {
    int j = blockIdx.x * blockDim.x + threadIdx.x;
    float nb = 0.0f;
    unsigned int nc = 0;
    if (j < NHITS) {
        float b = beta[j];
        int o = oid[j];
        float a = atanhf(b);
        float q = a * a + 0.1f;
        q_arr[j] = q;
        const float4* x4 = (const float4*)x;
        float4 A = x4[j * 3 + 0], B = x4[j * 3 + 1], C = x4[j * 3 + 2];
        xx_arr[j] = SS12(A, B, C);
        if (o > 0) {
            unsigned long long p =
                ((unsigned long long)__float_as_uint(q) << 32) |
                (unsigned long long)(0xFFFFFFFFu - (unsigned)j);
            atomicMax(&packed[o - 1], p);
        } else {
            nb = b; nc = 1;
        }
    }
    double rb = waveReduceD((double)nb);
    unsigned int rc = waveReduceU(nc);
    if ((threadIdx.x & 63) == 0) {
        if (rb != 0.0) atomicAdd(noise_sum, rb);
        if (rc)        atomicAdd(noise_cnt, (unsigned long long)rc);
    }
}

__global__ void k_alphas(const unsigned long long* __restrict__ packed,
                         const float* __restrict__ x,
                         const float* __restrict__ beta,
                         const float* __restrict__ q_arr,
                         const float* __restrict__ xx_arr,
                         float* __restrict__ arec,
                         double* __restrict__ coward_sum) {
    int k = blockIdx.x * blockDim.x + threadIdx.x;
    double c = 0.0;
    if (k < NOBJ) {
        unsigned idx = 0xFFFFFFFFu - (unsigned)(packed[k] & 0xFFFFFFFFull);
        const float4* x4 = (const float4*)x;
        float4 A = x4[idx * 3 + 0];
        float4 B = x4[idx * 3 + 1];
        float4 C = x4[idx * 3 + 2];
        float4 D;
        D.x = q_arr[idx]; D.y = xx_arr[idx]; D.z = 0.f; D.w = 0.f;
        float4* ar = (float4*)arec;
        ar[k * 4 + 0] = A;
        ar[k * 4 + 1] = B;
        ar[k * 4 + 2] = C;
        ar[k * 4 + 3] = D;
        c = 1.0 - (double)beta[idx];
    }
    double rc = waveReduceD(c);
    if ((threadIdx.x & 63) == 0) atomicAdd(coward_sum, rc);
}

// exact attractive term
__global__ void k_att(const float* __restrict__ x,
                      const int* __restrict__ oid,
                      const float* __restrict__ q_arr,
                      const float* __restrict__ xx_arr,
                      const float* __restrict__ arec,
                      double* __restrict__ v_att_sum) {
    int j = blockIdx.x * blockDim.x + threadIdx.x;
    double va = 0.0;
    if (j < NHITS) {
        int o = oid[j];
        if (o > 0) {
            int k = o - 1;
            const float4* x4 = (const float4*)x;
            float4 XA = x4[j * 3 + 0], XB = x4[j * 3 + 1], XC = x4[j * 3 + 2];
            const float4* ar = (const float4*)arec;
            float4 A = ar[k * 4 + 0], B = ar[k * 4 + 1], C = ar[k * 4 + 2], D = ar[k * 4 + 3];
            float dot = DOT12(XA, XB, XC, A, B, C);
            float d2r = fmaf(-2.0f, dot, xx_arr[j]) + D.y;
            va = (double)((q_arr[j] * D.x) * fmaxf(d2r, 0.0f));
        }
    }
    double rv = waveReduceD(va);
    if ((threadIdx.x & 63) == 0) {
        if (rv != 0.0) atomicAdd(v_att_sum, rv);
    }
}

// scan: build candidate masks (d2<1 & !att), count, write maskbuf (no atomic churn)
__global__ __launch_bounds__(256)
void k_scan(const float* __restrict__ x,
            const float* __restrict__ xx_arr,
            const int* __restrict__ oid,
            const float* __restrict__ arec,
            uint32_t* __restrict__ maskbuf,
            unsigned int* __restrict__ nrep,
            int do_write) {
    __shared__ unsigned int su[4];
    const int tid = threadIdx.x;
    const int t = blockIdx.x * 256 + tid;
    const bool valid = t < HALF;
    const int j0 = valid ? t : 0;
    const int j1 = j0 + HALF;
    const int kb = blockIdx.y * 128;
    const float4* x4 = (const float4*)x;
    const float4* ar4 = (const float4*)arec;

    v2f X[12];
    {
        float4 A0 = x4[j0 * 3 + 0], B0 = x4[j0 * 3 + 1], C0 = x4[j0 * 3 + 2];
        float4 A1 = x4[j1 * 3 + 0], B1 = x4[j1 * 3 + 1], C1 = x4[j1 * 3 + 2];
        X[0]  = (v2f){A0.x, A1.x}; X[1]  = (v2f){A0.y, A1.y};
        X[2]  = (v2f){A0.z, A1.z}; X[3]  = (v2f){A0.w, A1.w};
        X[4]  = (v2f){B0.x, B1.x}; X[5]  = (v2f){B0.y, B1.y};
        X[6]  = (v2f){B0.z, B1.z}; X[7]  = (v2f){B0.w, B1.w};
        X[8]  = (v2f){C0.x, C1.x}; X[9]  = (v2f){C0.y, C1.y};
        X[10] = (v2f){C0.z, C1.z}; X[11] = (v2f){C0.w, C1.w};
    }
    v2f xxp = (v2f){3e9f, 3e9f};
    if (valid) xxp = (v2f){xx_arr[j0], xx_arr[j1]};
    const int o0 = valid ? oid[j0] : 0;
    const int o1 = valid ? oid[j1] : 0;

    uint32_t w00 = 0, w01 = 0, w02 = 0, w03 = 0;
    uint32_t w10 = 0, w11 = 0, w12 = 0, w13 = 0;

#define SCAN_G(G, W0, W1)                                                   \
    {                                                                       \
        uint32_t bit = 1u;                                                  \
        for (int kk = 0; kk < 32; ++kk, bit += bit) {                       \
            int k = kb + (G) * 32 + kk;                                     \
            float4 A = ar4[k * 4 + 0];                                      \
            float4 B = ar4[k * 4 + 1];                                      \
            float4 C = ar4[k * 4 + 2];                                      \
            float a2 = ar4[k * 4 + 3].y;                                    \
            v2f dot = X[0] * (v2f){A.x, A.x};                               \
            dot = __builtin_elementwise_fma(X[1],  (v2f){A.y, A.y}, dot);   \
            dot = __builtin_elementwise_fma(X[2],  (v2f){A.z, A.z}, dot);   \
            dot = __builtin_elementwise_fma(X[3],  (v2f){A.w, A.w}, dot);   \
            dot = __builtin_elementwise_fma(X[4],  (v2f){B.x, B.x}, dot);   \
            dot = __builtin_elementwise_fma(X[5],  (v2f){B.y, B.y}, dot);   \
            dot = __builtin_elementwise_fma(X[6],  (v2f){B.z, B.z}, dot);   \
            dot = __builtin_elementwise_fma(X[7],  (v2f){B.w, B.w}, dot);   \
            dot = __builtin_elementwise_fma(X[8],  (v2f){C.x, C.x}, dot);   \
            dot = __builtin_elementwise_fma(X[9],  (v2f){C.y, C.y}, dot);   \
            dot = __builtin_elementwise_fma(X[10], (v2f){C.z, C.z}, dot);   \
            dot = __builtin_elementwise_fma(X[11], (v2f){C.w, C.w}, dot);   \
            v2f d2 = __builtin_elementwise_fma((v2f){-2.f, -2.f}, dot, xxp);\
            d2 = d2 + (v2f){a2, a2};                                        \
            W0 |= (d2[0] < 1.0f) ? bit : 0u;                                \
            W1 |= (d2[1] < 1.0f) ? bit : 0u;                                \
        }                                                                   \
    }
    SCAN_G(0, w00, w10)
    SCAN_G(1, w01, w11)
    SCAN_G(2, w02, w12)
    SCAN_G(3, w03, w13)
#undef SCAN_G

    // clear the (single) attractive bit if it lies in this 128-k window
    if (o0 > 0) {
        int rel = o0 - 1 - kb;
        if (rel >= 0 && rel < 128) {
            uint32_t b = 1u << (rel & 31);
            int g = rel >> 5;
            w00 &= (g == 0) ? ~b : 0xFFFFFFFFu;
            w01 &= (g == 1) ? ~b : 0xFFFFFFFFu;
            w02 &= (g == 2) ? ~b : 0xFFFFFFFFu;
            w03 &= (g == 3) ? ~b : 0xFFFFFFFFu;
        }
    }
    if (o1 > 0) {
        int rel = o1 - 1 - kb;
        if (rel >= 0 && rel < 128) {
            uint32_t b = 1u << (rel & 31);
            int g = rel >> 5;
            w10 &= (g == 0) ? ~b : 0xFFFFFFFFu;
            w11 &= (g == 1) ? ~b : 0xFFFFFFFFu;
            w12 &= (g == 2) ? ~b : 0xFFFFFFFFu;
            w13 &= (g == 3) ? ~b : 0xFFFFFFFFu;
        }
    }

    if (do_write && valid) {
        const int K = blockIdx.y * 4;
        maskbuf[(size_t)(K + 0) * NHITS + j0] = w00;
        maskbuf[(size_t)(K + 1) * NHITS + j0] = w01;
        maskbuf[(size_t)(K + 2) * NHITS + j0] = w02;
        maskbuf[(size_t)(K + 3) * NHITS + j0] = w03;
        maskbuf[(size_t)(K + 0) * NHITS + j1] = w10;
        maskbuf[(size_t)(K + 1) * NHITS + j1] = w11;
        maskbuf[(size_t)(K + 2) * NHITS + j1] = w12;
        maskbuf[(size_t)(K + 3) * NHITS + j1] = w13;
    }

    unsigned int cnt = (unsigned)(__popc(w00) + __popc(w01) + __popc(w02) + __popc(w03) +
                                  __popc(w10) + __popc(w11) + __popc(w12) + __popc(w13));
    unsigned int rc = waveReduceU(cnt);
    if ((tid & 63) == 0) su[tid >> 6] = rc;
    __syncthreads();
    if (tid == 0) {
        unsigned int s = su[0] + su[1] + su[2] + su[3];
        if (s) atomicAdd(nrep, s);
    }
}

__global__ void k_freq(const unsigned int* __restrict__ nrep,
                       float* __restrict__ freq) {
    unsigned int n = *nrep;
    if (n < 1u) n = 1u;
    float f = 100000.0f / (float)n;
    *freq = fminf(f, 1.0f);
}

// rep pass: grid over mask words; threefry per bit, d2 only on accept (~1.4%)
__global__ __launch_bounds__(256)
void k_rep(const float* __restrict__ x,
           const float* __restrict__ q_arr,
           const float* __restrict__ xx_arr,
           const float* __restrict__ arec,
           const uint32_t* __restrict__ maskbuf,
           const float* __restrict__ freq_ptr,
           double* __restrict__ acc_out) {
    __shared__ double sd[4];
    const int tid = threadIdx.x;
    const int j = blockIdx.x * 256 + tid;
    const int K = blockIdx.y;
    uint32_t word = (j < NHITS) ? maskbuf[(size_t)K * NHITS + j] : 0u;
    const float freq = *freq_ptr;
    double acc = 0.0;
    if (word) {
        const uint32_t fb = (uint32_t)j * NOBJ + (uint32_t)(K * 32);
        const bool lo = j < HALF;
        const float4* x4 = (const float4*)x;
        const float4* ar = (const float4*)arec;
        do {
            int b = (int)__builtin_ctz(word);
            word &= word - 1;
            uint32_t f = fb + (uint32_t)b;
            uint32_t xa = lo ? f : (f - HALF_PAIRS);
            uint32_t r0, r1;
            threefry2x32(0u, 42u, xa, xa + HALF_PAIRS, r0, r1);
            float u = tf_uniform(lo ? r0 : r1);
            if (u < freq) {
                int k = K * 32 + b;
                float4 XA = x4[j * 3 + 0], XB = x4[j * 3 + 1], XC = x4[j * 3 + 2];
                float4 A = ar[k * 4 + 0], B = ar[k * 4 + 1];
                float4 C = ar[k * 4 + 2], D = ar[k * 4 + 3];
                float dot = DOT12(XA, XB, XC, A, B, C);
                float d2 = fmaf(-2.0f, dot, xx_arr[j]) + D.y;
                float dist = sqrtf(fmaxf(fmaxf(d2, 0.0f), 1e-12f));
                acc += (double)((q_arr[j] * D.x) * (1.0f - dist));
            }
        } while (word);
    }
    double rv = waveReduceD(acc);
    if ((tid & 63) == 0) sd[tid >> 6] = rv;
    __syncthreads();
    if (tid == 0) {
        double s = sd[0] + sd[1] + sd[2] + sd[3];
        if (s != 0.0) atomicAdd(acc_out, s);
    }
}

// fallback (ws too small for maskbuf): rescan + inline sampling. Host-selected.
__global__ __launch_bounds__(256)
void k_rep_fb(const float* __restrict__ x,
              const float* __restrict__ q_arr,
              const float* __restrict__ xx_arr,
              const int* __restrict__ oid,
              const float* __restrict__ arec,
              const float* __restrict__ freq_ptr,
              double* __restrict__ acc_out) {
    __shared__ double sacc[4];
    const int tid = threadIdx.x;
    int t = blockIdx.x * 256 + tid;
    bool valid = t < HALF;
    int j0 = valid ? t : 0;
    int j1 = j0 + HALF;
    const float4* x4 = (const float4*)x;
    float4 X0a = x4[j0 * 3 + 0], X0b = x4[j0 * 3 + 1], X0c = x4[j0 * 3 + 2];
    float4 X1a = x4[j1 * 3 + 0], X1b = x4[j1 * 3 + 1], X1c = x4[j1 * 3 + 2];
    float xx0 = valid ? xx_arr[j0] : 3e9f;
    float xx1 = valid ? xx_arr[j1] : 3e9f;
    int o0 = oid[j0], o1 = oid[j1];
    const float4* ar = (const float4*)arec;
    const int kb = blockIdx.y * 128;
    const float freq = *freq_ptr;

    double acc = 0.0;
#define FB_G(G, J, XA, XB, XC, XX, OO, S1)                                      \
    {                                                                           \
        uint32_t m = 0, bit = 1u;                                               \
        int kbase = kb + (G) * 32;                                              \
        for (int kk = 0; kk < 32; ++kk, bit += bit) {                           \
            int k = kbase + kk;                                                 \
            float4 A = ar[k * 4 + 0];                                           \
            float4 B = ar[k * 4 + 1];                                           \
            float4 C = ar[k * 4 + 2];                                           \
            float a2 = ar[k * 4 + 3].y;                                         \
            float d0 = DOT12(XA, XB, XC, A, B, C);                              \
            float t0 = fmaf(-2.0f, d0, XX) + a2;                                \
            m |= (t0 < 1.0f && (OO) != k + 1) ? bit : 0u;                       \
        }                                                                       \
        while (m) {                                                             \
            int kk = __ffs(m) - 1; m &= m - 1;                                  \
            int k = kbase + kk;                                                 \
            uint32_t f = (uint32_t)(J) * NOBJ + (uint32_t)k;                    \
            uint32_t xa_ = (S1) ? (f - HALF_PAIRS) : f;                         \
            uint32_t b0_, b1_;                                                  \
            threefry2x32(0u, 42u, xa_, xa_ + HALF_PAIRS, b0_, b1_);             \
            float u = tf_uniform((S1) ? b1_ : b0_);                             \
            if (u < freq) {                                                     \
                float4 A = ar[k * 4 + 0], B = ar[k * 4 + 1], C = ar[k * 4 + 2], D = ar[k * 4 + 3]; \
                float dot = DOT12(XA, XB, XC, A, B, C);                         \
                float d2 = fmaf(-2.0f, dot, XX) + D.y;                          \
                float dist = sqrtf(fmaxf(fmaxf(d2, 0.0f), 1e-12f));             \
                acc += (double)((q_arr[J] * D.x) * (1.0f - dist));              \
            }                                                                   \
        }                                                                       \
    }
    FB_G(0, j0, X0a, X0b, X0c, xx0, o0, false)
    FB_G(1, j0, X0a, X0b, X0c, xx0, o0, false)
    FB_G(2, j0, X0a, X0b, X0c, xx0, o0, false)
    FB_G(3, j0, X0a, X0b, X0c, xx0, o0, false)
    FB_G(0, j1, X1a, X1b, X1c, xx1, o1, true)
    FB_G(1, j1, X1a, X1b, X1c, xx1, o1, true)
    FB_G(2, j1, X1a, X1b, X1c, xx1, o1, true)
    FB_G(3, j1, X1a, X1b, X1c, xx1, o1, true)
#undef FB_G

    double rv = waveReduceD(acc);
    if ((tid & 63) == 0) sacc[tid >> 6] = rv;
    __syncthreads();
    if (tid == 0) {
        double s = sacc[0] + sacc[1] + sacc[2] + sacc[3];
        if (s != 0.0) atomicAdd(acc_out, s);
    }
}

__global__ void k_final(const double* __restrict__ accs,
                        const unsigned long long* __restrict__ noise_cnt,
                        const float* __restrict__ freq,
                        float* __restrict__ out) {
    double v_att = accs[0] / (double)NHITS;
    double v_rep = accs[1] / (double)(*freq) / (double)NHITS;
    double l_cow = accs[2] / (double)NOBJ;
    unsigned long long nc = *noise_cnt;
    if (nc < 1ull) nc = 1ull;
    double l_noise = accs[3] / ((double)nc + 1e-9);
    double loss = v_att + v_rep + l_cow + 0.1 * l_noise;
    out[0] = (float)v_att;
    out[1] = (float)v_rep;
    out[2] = (float)l_cow;
    out[3] = (float)l_noise;
    out[4] = (float)loss;
}

// ---------------- launcher ----------------

extern "C" void kernel_launch(void* const* d_in, const int* in_sizes, int n_in,
                              void* d_out, int out_size, void* d_ws, size_t ws_size,
                              hipStream_t stream) {
    const float* beta = (const float*)d_in[0];
    const float* x    = (const float*)d_in[1];
    const int*   oid  = (const int*)d_in[2];
    float* out = (float*)d_out;

    char* ws = (char*)d_ws;
    double* v_att_sum = (double*)(ws + 0);
    double* v_rep_sum = (double*)(ws + 8);
    double* coward_sum = (double*)(ws + 16);
    double* noise_sum = (double*)(ws + 24);
    unsigned long long* noise_cnt = (unsigned long long*)(ws + 32);
    unsigned int* nrep = (unsigned int*)(ws + 40);
    float* freq = (float*)(ws + 48);
    unsigned long long* packed = (unsigned long long*)(ws + 64);
    float* arec = (float*)(ws + 8256);
    float* q_arr = (float*)(ws + 73792);
    float* xx_arr = (float*)(ws + 473792);
    uint32_t* maskbuf = (uint32_t*)(ws + MASK_OFF);

    const int wsok = (ws_size >= WS_NEED) ? 1 : 0;

    k_init<<<4, 256, 0, stream>>>(packed, (unsigned long long*)ws);
    k_hits<<<(NHITS + 255) / 256, 256, 0, stream>>>(beta, x, oid, packed,
                                                    q_arr, xx_arr,
                                                    noise_sum, noise_cnt);
    k_alphas<<<4, 256, 0, stream>>>(packed, x, beta, q_arr, xx_arr,
                                    arec, coward_sum);

    dim3 gs((HALF + 255) / 256, 8);
    k_scan<<<gs, 256, 0, stream>>>(x, xx_arr, oid, arec, maskbuf, nrep, wsok);

    k_att<<<(NHITS + 255) / 256, 256, 0, stream>>>(x, oid, q_arr, xx_arr,
                                                   arec, v_att_sum);
    k_freq<<<1, 1, 0, stream>>>(nrep, freq);

    if (wsok) {
        dim3 gr((NHITS + 255) / 256, 32);
        k_rep<<<gr, 256, 0, stream>>>(x, q_arr, xx_arr, arec, maskbuf,
                                      freq, v_rep_sum);
    } else {
        k_rep_fb<<<gs, 256, 0, stream>>>(x, q_arr, xx_arr, oid, arec,
                                         freq, v_rep_sum);
    }

    k_final<<<1, 1, 0, stream>>>((double*)ws, noise_cnt, freq, out);
}